// Round 13
// baseline (439.662 us; speedup 1.0000x reference)
//
#include <hip/hip_runtime.h>
#include <hip/hip_bf16.h>

// Problem constants
#define Bb 4
#define Ss 2048
#define DIMc 128
#define Hh 8
#define DHc 128
#define Mf 128
#define CH 128
#define NCc 16         // S / CHUNK
#define INNERc 1024    // H*DH
#define FFc 512

union F4 { float4 v; float f[4]; };
typedef unsigned short u16;

typedef __bf16 bf16x8 __attribute__((ext_vector_type(8)));
typedef float  f32x4  __attribute__((ext_vector_type(4)));

__device__ __forceinline__ unsigned fkey(float f){
  unsigned b = __float_as_uint(f);
  return (b & 0x80000000u) ? ~b : (b | 0x80000000u);
}
__device__ __forceinline__ float funkey(unsigned u){
  unsigned b = (u & 0x80000000u) ? (u & 0x7fffffffu) : ~u;
  return __uint_as_float(b);
}
__device__ __forceinline__ float gelu_f(float x){
  return 0.5f*x*(1.0f + tanhf(0.7978845608028654f*(x + 0.044715f*x*x*x)));
}
// f32 -> bf16 (RNE) raw
__device__ __forceinline__ u16 f2bu(float f){
  unsigned u = __float_as_uint(f);
  return (u16)((u + 0x7fffu + ((u>>16)&1u)) >> 16);
}
__device__ __forceinline__ float b2f(u16 u){
  return __uint_as_float(((unsigned)u)<<16);
}

// ---- swizzled bf16 LDS tile: [128][128] bf16 (32KB), byte = row*256+e*2,
// XOR ((row&7)<<4)  (G4 bank-conflict fix) ----
__device__ __forceinline__ bf16x8 ldfrag(const u16* base, int row, int e){
  int byte = (row*256 + e*2) ^ ((row&7)<<4);
  return *(const bf16x8*)((const char*)base + byte);
}
// stage bf16 row-major [128 x 128] (row stride srs elems) -> swizzled tile
__device__ __forceinline__ void stage_lin_bf(u16* dst, const u16* src, int srs, int t){
  #pragma unroll
  for(int it=0; it<8; ++it){
    int idx = t + it*256; int r = idx>>4, c8 = idx&15;
    int byte = (r*256 + c8*16) ^ ((r&7)<<4);
    *(uint4*)((char*)dst + byte) = *(const uint4*)(src + r*srs + c8*8);
  }
}
// stage bf16 row-major with per-element scale+offset: val*sc + off
__device__ __forceinline__ void stage_lin_bf_s(u16* dst, const u16* src, int srs,
    int t, float sc, float off){
  #pragma unroll
  for(int it=0; it<8; ++it){
    int idx = t + it*256; int r = idx>>4, c8 = idx&15;
    u16 tmp[8]; *(uint4*)tmp = *(const uint4*)(src + r*srs + c8*8);
    #pragma unroll
    for(int u=0;u<8;u++) tmp[u] = f2bu(fmaf(b2f(tmp[u]), sc, off));
    int byte = (r*256 + c8*16) ^ ((r&7)<<4);
    *(uint4*)((char*)dst + byte) = *(uint4*)tmp;
  }
}
// stage fp32 row-major [128 x 128] -> bf16 swizzled tile
__device__ __forceinline__ void stage_lin_f32(u16* dst, const float* src, int srs, int t){
  #pragma unroll
  for(int it=0; it<8; ++it){
    int idx = t + it*256; int r = idx>>4, c8 = idx&15;
    F4 v0, v1;
    v0.v = *(const float4*)(src + r*srs + c8*8);
    v1.v = *(const float4*)(src + r*srs + c8*8 + 4);
    u16 tmp[8];
    #pragma unroll
    for(int u=0;u<4;u++){ tmp[u] = f2bu(v0.f[u]); tmp[4+u] = f2bu(v1.f[u]); }
    int byte = (r*256 + c8*16) ^ ((r&7)<<4);
    *(uint4*)((char*)dst + byte) = *(uint4*)tmp;
  }
}
// stage TRANSPOSED from bf16 source: dst[d][j] = src[j][d]
__device__ __forceinline__ void stage_tr_bf(u16* dst, const u16* src, int srs, int t){
  int j0 = (t & 63)*2; int wv = t>>6;
  #pragma unroll
  for(int it=0; it<2; ++it){
    int d0 = wv*16 + it*64;
    u16 a0[16], a1[16];
    *(uint4*)&a0[0] = *(const uint4*)(src + j0*srs + d0);
    *(uint4*)&a0[8] = *(const uint4*)(src + j0*srs + d0 + 8);
    *(uint4*)&a1[0] = *(const uint4*)(src + (j0+1)*srs + d0);
    *(uint4*)&a1[8] = *(const uint4*)(src + (j0+1)*srs + d0 + 8);
    #pragma unroll
    for(int dc=0; dc<16; ++dc){
      int d = d0 + dc;
      unsigned pk = (unsigned)a0[dc] | ((unsigned)a1[dc]<<16);
      int byte = (d*256 + j0*2) ^ ((d&7)<<4);
      *(unsigned*)((char*)dst + byte) = pk;
    }
  }
}
// stage TRANSPOSED from bf16 source with per-element scale+offset
__device__ __forceinline__ void stage_tr_bf_s(u16* dst, const u16* src, int srs,
    int t, float sc, float off){
  int j0 = (t & 63)*2; int wv = t>>6;
  #pragma unroll
  for(int it=0; it<2; ++it){
    int d0 = wv*16 + it*64;
    u16 a0[16], a1[16];
    *(uint4*)&a0[0] = *(const uint4*)(src + j0*srs + d0);
    *(uint4*)&a0[8] = *(const uint4*)(src + j0*srs + d0 + 8);
    *(uint4*)&a1[0] = *(const uint4*)(src + (j0+1)*srs + d0);
    *(uint4*)&a1[8] = *(const uint4*)(src + (j0+1)*srs + d0 + 8);
    #pragma unroll
    for(int dc=0; dc<16; ++dc){
      int d = d0 + dc;
      unsigned pk = (unsigned)f2bu(fmaf(b2f(a0[dc]), sc, off)) |
                    ((unsigned)f2bu(fmaf(b2f(a1[dc]), sc, off))<<16);
      int byte = (d*256 + j0*2) ^ ((d&7)<<4);
      *(unsigned*)((char*)dst + byte) = pk;
    }
  }
}

// bijective XCD-aware tile swizzle: returns (tile_n, tile_m)
__device__ __forceinline__ int2 swz_tile(){
  int nx = gridDim.x;
  int nwg = gridDim.x*gridDim.y;
  int lin = blockIdx.y*nx + blockIdx.x;
  int q = nwg>>3, r = nwg&7;
  int xcd = lin&7, idx = lin>>3;
  int nl = (xcd<r) ? (xcd*(q+1)+idx) : (r*(q+1)+(xcd-r)*q+idx);
  return make_int2(nl % nx, nl / nx);
}
// 1D bijective swizzle (nwg % 8 == 0)
__device__ __forceinline__ int swz_lin(){
  int nwg = gridDim.x;
  int lin = blockIdx.x;
  int q = nwg>>3;
  return (lin&7)*q + (lin>>3);
}

// ------- embedding + layer-0 LN1 fused (+ kstab init in block 0) ---------
__global__ __launch_bounds__(256) void k_embed_ln(const float* __restrict__ x,
    const float* __restrict__ lw, const float* __restrict__ lb,
    const float* __restrict__ pe, const float* __restrict__ g,
    const float* __restrict__ bta, float* __restrict__ h,
    u16* __restrict__ y, unsigned* __restrict__ kstab){
  if(blockIdx.x==0 && threadIdx.x<64) kstab[threadIdx.x] = 0u;
  int wave = threadIdx.x >> 6; int lane = threadIdx.x & 63;
  int row = blockIdx.x*4 + wave;
  int s = row & (Ss-1);
  float xv = x[row];
  float x1 = xv*lw[lane]    + lb[lane]    + pe[s*DIMc + lane];
  float x2 = xv*lw[lane+64] + lb[lane+64] + pe[s*DIMc + lane+64];
  h[row*DIMc+lane]    = x1;
  h[row*DIMc+lane+64] = x2;
  float sm = x1+x2, sq = x1*x1 + x2*x2;
  #pragma unroll
  for(int m=1;m<64;m<<=1){ sm += __shfl_xor(sm,m,64); sq += __shfl_xor(sq,m,64); }
  float mu = sm * (1.0f/128.0f);
  float var = sq*(1.0f/128.0f) - mu*mu;
  float rs = rsqrtf(var + 1e-5f);
  y[row*DIMc+lane]    = f2bu((x1-mu)*rs*g[lane]+bta[lane]);
  y[row*DIMc+lane+64] = f2bu((x2-mu)*rs*g[lane+64]+bta[lane+64]);
}

// --------- prep: transpose+convert wo/ff2 weights to bf16 [N][K] ---------
__global__ __launch_bounds__(256) void k_prep(const float* __restrict__ wo,
    const float* __restrict__ ff2, u16* __restrict__ woT, u16* __restrict__ ff2T){
  int blk = blockIdx.x;
  if(blk < 1024){
    int idx = blk*256 + threadIdx.x;        // over 2*128*1024
    int k = idx & 1023; int n = (idx>>10) & 127; int l = idx>>17;
    woT[idx] = f2bu(wo[l*131072 + k*128 + n]);
  } else {
    int idx = (blk-1024)*256 + threadIdx.x; // over 2*128*512
    int k = idx & 511; int n = (idx>>9) & 127; int l = idx>>16;
    ff2T[idx] = f2bu(ff2[l*65536 + k*128 + n]);
  }
}

// ------------ 128x128 K-resident MFMA GEMM (K=128), bf16 A, fp32 W -------
template<bool QKV3, bool BIAS, bool GELU>
__global__ __launch_bounds__(256) void k_gemm128(const u16* __restrict__ A,
    const float* __restrict__ B0, const float* __restrict__ B1,
    const float* __restrict__ B2, const float* __restrict__ bias,
    u16* __restrict__ C0, u16* __restrict__ C1, u16* __restrict__ C2,
    int N){
  __shared__ __align__(16) u16 As[16384];
  __shared__ __align__(16) u16 Bs[16384];
  int2 tt = swz_tile();
  int tn = tt.x, m0 = tt.y*128;
  const float* Bw; u16* C; int n0;
  if(QKV3){
    int tpw = N>>7;
    int widx = tn / tpw; n0 = (tn % tpw)*128;
    Bw = (widx==0) ? B0 : ((widx==1) ? B1 : B2);
    C  = (widx==0) ? C0 : ((widx==1) ? C1 : C2);
  } else { Bw = B0; C = C0; n0 = tn*128; }
  int t = threadIdx.x; int lane = t&63, w = t>>6;
  int fr = lane&15, kc = lane>>4;
  stage_lin_bf(As, A + (size_t)m0*128, 128, t);
  {
    #pragma unroll
    for(int it=0; it<8; ++it){
      int idx = t + it*256; int n = idx&127, c8 = idx>>7;
      u16 tmp[8];
      #pragma unroll
      for(int j=0;j<8;j++) tmp[j] = f2bu(Bw[(c8*8+j)*N + n0 + n]);
      int byte = (n*256 + c8*16) ^ ((n&7)<<4);
      *(uint4*)((char*)Bs + byte) = *(uint4*)tmp;
    }
  }
  __syncthreads();
  f32x4 acc[2][8] = {};
  #pragma unroll
  for(int ks=0; ks<4; ++ks){
    bf16x8 a[2];
    #pragma unroll
    for(int i=0;i<2;i++) a[i] = ldfrag(As, w*32+i*16+fr, ks*32+kc*8);
    bf16x8 bm[8];
    #pragma unroll
    for(int cb=0;cb<8;cb++) bm[cb] = ldfrag(Bs, cb*16+fr, ks*32+kc*8);
    #pragma unroll
    for(int i=0;i<2;i++)
      #pragma unroll
      for(int cb=0;cb<8;cb++)
        acc[i][cb] = __builtin_amdgcn_mfma_f32_16x16x32_bf16(a[i], bm[cb], acc[i][cb], 0,0,0);
  }
  #pragma unroll
  for(int i=0;i<2;i++){
    #pragma unroll
    for(int r=0;r<4;r++){
      int row = m0 + w*32 + i*16 + kc*4 + r;
      #pragma unroll
      for(int cb=0;cb<8;cb++){
        int col = n0 + cb*16 + fr;
        float val = acc[i][cb][r];
        if(BIAS) val += bias[col];
        if(GELU) val = gelu_f(val);
        C[(size_t)row*N + col] = f2bu(val);
      }
    }
  }
}

// --- direct-fragment GEMM + residual + optional fused LayerNorm ----------
// A bf16 [M][K], BT bf16 [128][K]. h fp32 [M][128]: h += A@B + bias.
// DOLN: y = LN(h) bf16 with (g,b). Grid 256 blocks, 32 rows each, all cols.
// waves: rg = w>>1 (16-row group), ch = w&1 (64-col half).
template<bool DOLN>
__global__ __launch_bounds__(256) void k_gemm_direct_ln(const u16* __restrict__ A,
    const u16* __restrict__ BT, const float* __restrict__ bias,
    float* __restrict__ h, const float* __restrict__ g,
    const float* __restrict__ bta, u16* __restrict__ y, int K){
  __shared__ float sums_s[32][2], sqs_s[32][2];
  int m0 = swz_lin()*32;
  int t = threadIdx.x; int w = t>>6, lane = t&63;
  int rg = w>>1, ch = w&1;
  int fr = lane&15, kc = lane>>4;
  const u16* ap = A + (size_t)(m0+rg*16+fr)*K + kc*8;
  const u16* bp[4];
  #pragma unroll
  for(int cb=0;cb<4;cb++) bp[cb] = BT + (size_t)(ch*64+cb*16+fr)*K + kc*8;
  f32x4 acc[4] = {};
  #pragma unroll 4
  for(int k0=0; k0<K; k0+=32){
    bf16x8 af = *(const bf16x8*)(ap + k0);
    #pragma unroll
    for(int cb=0;cb<4;cb++){
      bf16x8 bf = *(const bf16x8*)(bp[cb] + k0);
      acc[cb] = __builtin_amdgcn_mfma_f32_16x16x32_bf16(af, bf, acc[cb], 0,0,0);
    }
  }
  // epilogue: residual add, per-row partial sums
  float hv[4][4];
  #pragma unroll
  for(int r=0;r<4;r++){
    int row = m0 + rg*16 + kc*4 + r;
    float s = 0.f, sq = 0.f;
    #pragma unroll
    for(int cb=0;cb<4;cb++){
      int col = ch*64 + cb*16 + fr;
      float val = acc[cb][r] + bias[col] + h[(size_t)row*128+col];
      h[(size_t)row*128+col] = val;
      hv[r][cb] = val;
      if(DOLN){ s += val; sq += val*val; }
    }
    if(DOLN){
      #pragma unroll
      for(int msk=1;msk<16;msk<<=1){ s += __shfl_xor(s,msk,64); sq += __shfl_xor(sq,msk,64); }
      if(fr==0){ sums_s[rg*16+kc*4+r][ch] = s; sqs_s[rg*16+kc*4+r][ch] = sq; }
    }
  }
  if(DOLN){
    __syncthreads();
    #pragma unroll
    for(int r=0;r<4;r++){
      int rw = rg*16 + kc*4 + r;
      int row = m0 + rw;
      float s  = sums_s[rw][0] + sums_s[rw][1];
      float sq = sqs_s[rw][0] + sqs_s[rw][1];
      float mu = s * (1.0f/128.0f);
      float var = sq*(1.0f/128.0f) - mu*mu;
      float rs = rsqrtf(var + 1e-5f);
      #pragma unroll
      for(int cb=0;cb<4;cb++){
        int col = ch*64 + cb*16 + fr;
        y[(size_t)row*128+col] = f2bu((hv[r][cb]-mu)*rs*g[col] + bta[col]);
      }
    }
  }
}

// ------------- FAVOR+ features via MFMA, q+k in ONE dispatch -------------
__global__ __launch_bounds__(256) void k_featboth(
    u16* __restrict__ qbuf, u16* __restrict__ kbuf,
    const float* __restrict__ proj, unsigned* __restrict__ kstab){
  __shared__ __align__(16) u16 xs[16384];
  __shared__ __align__(16) u16 ps[16384];
  __shared__ float diag_s[128];
  __shared__ unsigned hmax[8];
  int blk = blockIdx.x;
  bool isq = blk < 512;
  int r0 = (blk & 511)*128;
  u16* xin = isq ? qbuf : kbuf;
  int t = threadIdx.x; int lane = t&63, w = t>>6;
  int fr = lane&15, kc = lane>>4;
  const float norm  = 0.29730177875068026f;   // 128^-0.25
  const float ratio = 0.08838834764831845f;   // 128^-0.5
  if(!isq && t<8) hmax[t] = 0u;
  stage_lin_bf(xs, xin + (size_t)r0*128, 128, t);
  stage_lin_f32(ps, proj, 128, t);
  { // diag: 2 threads per row, 64 elems each
    int r = t>>1, half = t&1;
    const u16* rp = xin + (size_t)(r0+r)*128 + half*64;
    float ss = 0.f;
    #pragma unroll
    for(int u4=0; u4<8; ++u4){
      u16 tmp[8]; *(uint4*)tmp = *(const uint4*)(rp + u4*8);
      #pragma unroll
      for(int u=0;u<8;u++){ float f = b2f(tmp[u]); ss += f*f; }
    }
    ss += __shfl_xor(ss, 1, 64);
    if(half==0) diag_s[r] = 0.5f*norm*norm*ss;
  }
  __syncthreads();
  f32x4 acc[2][8] = {};
  #pragma unroll
  for(int ks=0; ks<4; ++ks){
    bf16x8 a[2];
    #pragma unroll
    for(int i=0;i<2;i++) a[i] = ldfrag(xs, w*32+i*16+fr, ks*32+kc*8);
    bf16x8 bm[8];
    #pragma unroll
    for(int cb=0;cb<8;cb++) bm[cb] = ldfrag(ps, cb*16+fr, ks*32+kc*8);
    #pragma unroll
    for(int i=0;i<2;i++)
      #pragma unroll
      for(int cb=0;cb<8;cb++)
        acc[i][cb] = __builtin_amdgcn_mfma_f32_16x16x32_bf16(a[i], bm[cb], acc[i][cb], 0,0,0);
  }
  __syncthreads();   // all xs/ps reads complete before reuse
  #pragma unroll
  for(int i=0;i<2;i++){
    #pragma unroll
    for(int r=0;r<4;r++){
      int row = w*32 + i*16 + kc*4 + r;
      float dg = diag_s[row];
      float rmax = acc[i][0][r];
      #pragma unroll
      for(int cb=1;cb<8;cb++) rmax = fmaxf(rmax, acc[i][cb][r]);
      #pragma unroll
      for(int msk=1;msk<16;msk<<=1) rmax = fmaxf(rmax, __shfl_xor(rmax, msk, 64));
      if(isq){
        float base = -dg - norm*rmax;
        #pragma unroll
        for(int cb=0;cb<8;cb++){
          float val = ratio*(expf(fmaf(norm, acc[i][cb][r], base)) + 1e-4f);
          int byte = (row*256 + (cb*16+fr)*2) ^ ((row&7)<<4);
          *(u16*)((char*)xs + byte) = f2bu(val);
        }
      } else {
        if(fr==0) atomicMax(&hmax[row&7], fkey(norm*rmax));
        #pragma unroll
        for(int cb=0;cb<8;cb++){
          float val = expf(fmaf(norm, acc[i][cb][r], -dg));
          int byte = (row*256 + (cb*16+fr)*2) ^ ((row&7)<<4);
          *(u16*)((char*)xs + byte) = f2bu(val);
        }
      }
    }
  }
  __syncthreads();
  // coalesced copy out of the restaged tile
  #pragma unroll
  for(int it=0; it<8; ++it){
    int idx = t + it*256; int r = idx>>4, c8 = idx&15;
    int byte = (r*256 + c8*16) ^ ((r&7)<<4);
    *(uint4*)(xin + (size_t)(r0+r)*128 + c8*8) = *(uint4*)((char*)xs + byte);
  }
  if(!isq){
    int b = r0 >> 14;
    if(t<8) atomicMax(&kstab[b*8 + t], hmax[t]);
  }
}

// ------------- attention phase 1 (MFMA): kv = kp^T v, ksum = sum kp ------
__global__ __launch_bounds__(256) void k_attn1m(const u16* __restrict__ kp,
    const u16* __restrict__ v, u16* __restrict__ kvc, float* __restrict__ ksc,
    const unsigned* __restrict__ kstab){
  __shared__ __align__(16) u16 kt[16384];
  __shared__ __align__(16) u16 vt[16384];
  int bc = blockIdx.x; int c = bc&15, bh = bc>>4, b = bh>>3, hh = bh&7;
  int t = threadIdx.x; int lane = t&63, w = t>>6;
  int fr = lane&15, kc = lane>>4;
  int s0 = c*128;
  const float ratio = 0.08838834764831845f;
  float stab = funkey(kstab[bh]);
  float csc = ratio * expf(-stab);
  float reps = ratio * 1e-4f;
  const u16* kb = kp + (size_t)((b*Ss+s0)*Hh + hh)*128;
  const u16* vb = v  + (size_t)((b*Ss+s0)*Hh + hh)*128;
  stage_tr_bf_s(kt, kb, 1024, t, csc, reps);
  stage_tr_bf(vt, vb, 1024, t);
  __syncthreads();
  f32x4 acc[2][8] = {};
  f32x4 ks[2] = {};
  bf16x8 bones;
  #pragma unroll
  for(int e=0;e<8;e++) bones[e] = (fr==0) ? (__bf16)1.0f : (__bf16)0.0f;
  #pragma unroll
  for(int js=0;js<4;js++){
    bf16x8 am[2];
    #pragma unroll
    for(int i=0;i<2;i++) am[i] = ldfrag(kt, w*32+i*16+fr, js*32+kc*8);
    bf16x8 bv[8];
    #pragma unroll
    for(int cb=0;cb<8;cb++) bv[cb] = ldfrag(vt, cb*16+fr, js*32+kc*8);
    #pragma unroll
    for(int i=0;i<2;i++){
      ks[i] = __builtin_amdgcn_mfma_f32_16x16x32_bf16(am[i], bones, ks[i], 0,0,0);
      #pragma unroll
      for(int cb=0;cb<8;cb++)
        acc[i][cb] = __builtin_amdgcn_mfma_f32_16x16x32_bf16(am[i], bv[cb], acc[i][cb], 0,0,0);
    }
  }
  u16* kvb = kvc + (size_t)bc*16384;
  #pragma unroll
  for(int i=0;i<2;i++){
    #pragma unroll
    for(int r=0;r<4;r++){
      int m = w*32 + i*16 + kc*4 + r;
      #pragma unroll
      for(int cb=0;cb<8;cb++) kvb[m*128 + cb*16 + fr] = f2bu(acc[i][cb][r]);
      if(fr==0) ksc[bc*128 + m] = ks[i][r];
    }
  }
}

// --- phase 1.5 fused: blocks 0..1023 scan kvc (bf16 pairs), 1024..1039 ksc
__global__ __launch_bounds__(256) void k_prefix2(unsigned* __restrict__ kvc,
    float* __restrict__ ksc){
  int blk = blockIdx.x;
  if(blk < 1024){
    int bh = blk >> 5; int pos = (blk & 31)*256 + threadIdx.x; // uint idx
    int base = bh*16*8192 + pos;
    float a0 = 0.f, a1 = 0.f;
    #pragma unroll
    for(int c=0;c<16;c++){
      unsigned pk = kvc[base + c*8192];
      float x0 = b2f((u16)pk), x1 = b2f((u16)(pk>>16));
      kvc[base + c*8192] = (unsigned)f2bu(a0) | ((unsigned)f2bu(a1)<<16);
      a0 += x0; a1 += x1;
    }
  } else {
    int e = (blk-1024)*256 + threadIdx.x;
    int bh = e>>7, m = e&127;
    float a = 0.f;
    #pragma unroll
    for(int c=0;c<16;c++){
      int idx = (bh*16+c)*128 + m;
      float xv = ksc[idx]; ksc[idx] = a; a += xv;
    }
  }
}

// ------------- attention phase 2 (MFMA): per-chunk output ----------------
__global__ __launch_bounds__(256) void k_attn2m(const u16* __restrict__ qp,
    const u16* __restrict__ kp, const u16* __restrict__ v,
    const u16* __restrict__ kvc, const float* __restrict__ ksc,
    u16* __restrict__ o, const unsigned* __restrict__ kstab){
  __shared__ __align__(16) u16 qs[16384];  // qp -> P
  __shared__ __align__(16) u16 bs[16384];  // kp -> v^T -> kv^T
  __shared__ float ksum_s[128];
  int bc = blockIdx.x; int c = bc&15, bh = bc>>4, b = bh>>3, hh = bh&7;
  int t = threadIdx.x; int lane = t&63, w = t>>6;
  int fr = lane&15, kc = lane>>4;
  int s0 = c*128;
  const float ratio = 0.08838834764831845f;
  float stab = funkey(kstab[bh]);
  float csc = ratio * expf(-stab);
  float reps = ratio * 1e-4f;
  const u16* qb = qp + (size_t)((b*Ss+s0)*Hh + hh)*128;
  const u16* kb = kp + (size_t)((b*Ss+s0)*Hh + hh)*128;
  const u16* vb = v  + (size_t)((b*Ss+s0)*Hh + hh)*128;
  const u16* kvb = kvc + (size_t)bc*16384;
  stage_lin_bf(qs, qb, 1024, t);
  stage_lin_bf_s(bs, kb, 1024, t, csc, reps);
  if(t<128) ksum_s[t] = ksc[bc*128 + t];
  __syncthreads();
  bf16x8 aq[2][4];
  #pragma unroll
  for(int i=0;i<2;i++)
    #pragma unroll
    for(int ks=0;ks<4;ks++)
      aq[i][ks] = ldfrag(qs, w*32+i*16+fr, ks*32+kc*8);
  // S = qp @ kp^T
  f32x4 sacc[2][8] = {};
  #pragma unroll
  for(int ks=0;ks<4;ks++){
    bf16x8 bk[8];
    #pragma unroll
    for(int cb=0;cb<8;cb++) bk[cb] = ldfrag(bs, cb*16+fr, ks*32+kc*8);
    #pragma unroll
    for(int i=0;i<2;i++)
      #pragma unroll
      for(int cb=0;cb<8;cb++)
        sacc[i][cb] = __builtin_amdgcn_mfma_f32_16x16x32_bf16(aq[i][ks], bk[cb], sacc[i][cb], 0,0,0);
  }
  __syncthreads();
  // masked P -> qs (bf16); stage v^T -> bs
  #pragma unroll
  for(int i=0;i<2;i++){
    #pragma unroll
    for(int cb=0;cb<8;cb++){
      #pragma unroll
      for(int r=0;r<4;r++){
        int prow = w*32 + i*16 + kc*4 + r;
        int pcol = cb*16 + fr;
        float pv = (pcol > prow) ? 0.f : sacc[i][cb][r];
        int byte = (prow*256 + pcol*2) ^ ((prow&7)<<4);
        *(u16*)((char*)qs + byte) = f2bu(pv);
      }
    }
  }
  stage_tr_bf(bs, vb, 1024, t);
  __syncthreads();
  // num = P @ v ; den = P @ ones
  f32x4 nacc[2][8] = {};
  f32x4 dacc[2] = {};
  bf16x8 bones;
  #pragma unroll
  for(int e=0;e<8;e++) bones[e] = (fr==0) ? (__bf16)1.0f : (__bf16)0.0f;
  #pragma unroll
  for(int js=0;js<4;js++){
    bf16x8 ap[2];
    #pragma unroll
    for(int i=0;i<2;i++) ap[i] = ldfrag(qs, w*32+i*16+fr, js*32+kc*8);
    bf16x8 bv[8];
    #pragma unroll
    for(int cb=0;cb<8;cb++) bv[cb] = ldfrag(bs, cb*16+fr, js*32+kc*8);
    #pragma unroll
    for(int i=0;i<2;i++){
      dacc[i] = __builtin_amdgcn_mfma_f32_16x16x32_bf16(ap[i], bones, dacc[i], 0,0,0);
      #pragma unroll
      for(int cb=0;cb<8;cb++)
        nacc[i][cb] = __builtin_amdgcn_mfma_f32_16x16x32_bf16(ap[i], bv[cb], nacc[i][cb], 0,0,0);
    }
  }
  __syncthreads();
  stage_tr_bf(bs, kvb, 128, t);
  __syncthreads();
  // num += qp @ kv_excl ; den += qp @ ksum_excl
  #pragma unroll
  for(int ms=0;ms<4;ms++){
    bf16x8 bkv[8];
    #pragma unroll
    for(int cb=0;cb<8;cb++) bkv[cb] = ldfrag(bs, cb*16+fr, ms*32+kc*8);
    bf16x8 bks;
    #pragma unroll
    for(int e=0;e<8;e++) bks[e] = (fr==0) ? (__bf16)ksum_s[ms*32+kc*8+e] : (__bf16)0.0f;
    #pragma unroll
    for(int i=0;i<2;i++){
      dacc[i] = __builtin_amdgcn_mfma_f32_16x16x32_bf16(aq[i][ms], bks, dacc[i], 0,0,0);
      #pragma unroll
      for(int cb=0;cb<8;cb++)
        nacc[i][cb] = __builtin_amdgcn_mfma_f32_16x16x32_bf16(aq[i][ms], bkv[cb], nacc[i][cb], 0,0,0);
    }
  }
  #pragma unroll
  for(int i=0;i<2;i++){
    #pragma unroll
    for(int r=0;r<4;r++){
      float den = __shfl(dacc[i][r], lane & 48, 64);
      float inv = 1.0f/(den + 1e-6f);
      int row = w*32 + i*16 + kc*4 + r;
      u16* ob = o + (size_t)((b*Ss+s0+row)*Hh + hh)*128;
      #pragma unroll
      for(int cb=0;cb<8;cb++)
        ob[cb*16 + fr] = f2bu(nacc[i][cb][r] * inv);
    }
  }
}

// ------------- pooling + classifier --------------------------------------
__global__ __launch_bounds__(256) void k_pool(const float* __restrict__ h,
    float* __restrict__ pw){
  __shared__ float part[256];
  int blk = blockIdx.x; int b = blk>>4, c = blk&15;
  int t = threadIdx.x; int half = t>>7;
  float s = 0.f;
  int s0 = c*128 + half*64;
  for(int si=s0; si<s0+64; ++si) s += h[(b*Ss+si)*128 + (t&127)];
  part[t] = s;
  __syncthreads();
  if(t<128) pw[blk*128 + t] = part[t] + part[t+128];
}
__global__ __launch_bounds__(128) void k_cls(const float* __restrict__ pw,
    const float* __restrict__ fw, const float* __restrict__ fb,
    float* __restrict__ out){
  __shared__ float pool_s[128];
  int b = blockIdx.x; int t = threadIdx.x;
  float s = 0.f;
  for(int c=0;c<16;c++) s += pw[(b*16+c)*128 + t];
  pool_s[t] = s * (1.0f/2048.0f);
  __syncthreads();
  if(t<10){
    float a = fb[t];
    for(int d=0; d<128; ++d) a += pool_s[d]*fw[d*10+t];
    out[b*10+t] = a;
  }
}

extern "C" void kernel_launch(void* const* d_in, const int* in_sizes, int n_in,
                              void* d_out, int out_size, void* d_ws, size_t ws_size,
                              hipStream_t stream){
  (void)in_sizes; (void)n_in; (void)out_size; (void)ws_size;
  const float* x     = (const float*)d_in[0];
  const float* lin_w = (const float*)d_in[1];
  const float* lin_b = (const float*)d_in[2];
  const float* pe    = (const float*)d_in[3];
  const float* proj  = (const float*)d_in[4];
  const float* ln1_g = (const float*)d_in[5];
  const float* ln1_b = (const float*)d_in[6];
  const float* wq    = (const float*)d_in[7];
  const float* wk    = (const float*)d_in[8];
  const float* wv    = (const float*)d_in[9];
  const float* wo    = (const float*)d_in[10];
  const float* wo_b  = (const float*)d_in[11];
  const float* ln2_g = (const float*)d_in[12];
  const float* ln2_b = (const float*)d_in[13];
  const float* ff1w  = (const float*)d_in[14];
  const float* ff1b  = (const float*)d_in[15];
  const float* ff2w  = (const float*)d_in[16];
  const float* ff2b  = (const float*)d_in[17];
  const float* finw  = (const float*)d_in[18];
  const float* finb  = (const float*)d_in[19];
  float* out = (float*)d_out;

  // workspace layout (in floats; bf16 buffers use half-float slots)
  float* ws  = (float*)d_ws;
  float* h    = ws;               // fp32 [8192][128]
  u16*  y    = (u16*)(h + 1048576);               // bf16 [8192][128]
  u16*  q    = (u16*)(h + 1048576 + 524288);      // bf16 [8192][1024]
  u16*  k    = q + 8388608;       // bf16 [8192][1024]
  u16*  v    = k + 8388608;       // bf16
  u16*  o    = v + 8388608;       // bf16
  u16*  kvc  = o + 8388608;       // bf16 [32][16][128][128]
  float* ksc  = (float*)(kvc + 8388608);  // fp32 [32][16][128]
  float* pw   = ksc + 65536;
  unsigned* kstab = (unsigned*)(pw + 8192);   // [2][32]
  u16*  woT  = (u16*)(kstab + 64);            // bf16 [2][128][1024]
  u16*  ff2T = woT + 262144;                  // bf16 [2][128][512]

  k_embed_ln<<<2048,256,0,stream>>>(x, lin_w, lin_b, pe, ln1_g, ln1_b, h, y, kstab);
  k_prep<<<1536,256,0,stream>>>(wo, ff2w, woT, ff2T);
  for(int l=0;l<2;l++){
    const float* projl = proj + l*Mf*DHc;
    k_gemm128<true,false,false><<<dim3(24,64),256,0,stream>>>(
        y, wq + l*DIMc*INNERc, wk + l*DIMc*INNERc, wv + l*DIMc*INNERc,
        nullptr, q, k, v, INNERc);
    k_featboth<<<1024,256,0,stream>>>(q, k, projl, kstab + l*32);
    k_attn1m<<<512,256,0,stream>>>(k, v, kvc, ksc, kstab + l*32);
    k_prefix2<<<1040,256,0,stream>>>((unsigned*)kvc, ksc);
    k_attn2m<<<512,256,0,stream>>>(q, k, v, kvc, ksc, o, kstab + l*32);
    // WO + residual + fused LN2
    k_gemm_direct_ln<true><<<256,256,0,stream>>>(o, woT + l*131072,
        wo_b + l*DIMc, h, ln2_g + l*DIMc, ln2_b + l*DIMc, y, INNERc);
    k_gemm128<false,true,true><<<dim3(4,64),256,0,stream>>>(
        y, ff1w + l*DIMc*FFc, nullptr, nullptr, ff1b + l*FFc,
        q, nullptr, nullptr, FFc);
    // FF2 + residual + fused LN1 of next layer (skip after last layer)
    if(l==0)
      k_gemm_direct_ln<true><<<256,256,0,stream>>>(q, ff2T + l*65536,
          ff2b + l*DIMc, h, ln1_g + (l+1)*DIMc, ln1_b + (l+1)*DIMc, y, FFc);
    else
      k_gemm_direct_ln<false><<<256,256,0,stream>>>(q, ff2T + l*65536,
          ff2b + l*DIMc, h, nullptr, nullptr, nullptr, FFc);
  }
  k_pool<<<64,256,0,stream>>>(h, pw);
  k_cls<<<4,128,0,stream>>>(pw, finw, finb, out);
}

// Round 14
// 400.574 us; speedup vs baseline: 1.0976x; 1.0976x over previous
//
#include <hip/hip_runtime.h>
#include <hip/hip_bf16.h>

// Problem constants
#define Bb 4
#define Ss 2048
#define DIMc 128
#define Hh 8
#define DHc 128
#define Mf 128
#define CH 128
#define NCc 16         // S / CHUNK
#define INNERc 1024    // H*DH
#define FFc 512

union F4 { float4 v; float f[4]; };
typedef unsigned short u16;

typedef __bf16 bf16x8 __attribute__((ext_vector_type(8)));
typedef float  f32x4  __attribute__((ext_vector_type(4)));

__device__ __forceinline__ unsigned fkey(float f){
  unsigned b = __float_as_uint(f);
  return (b & 0x80000000u) ? ~b : (b | 0x80000000u);
}
__device__ __forceinline__ float funkey(unsigned u){
  unsigned b = (u & 0x80000000u) ? (u & 0x7fffffffu) : ~u;
  return __uint_as_float(b);
}
__device__ __forceinline__ float gelu_f(float x){
  return 0.5f*x*(1.0f + tanhf(0.7978845608028654f*(x + 0.044715f*x*x*x)));
}
// f32 -> bf16 (RNE) raw
__device__ __forceinline__ u16 f2bu(float f){
  unsigned u = __float_as_uint(f);
  return (u16)((u + 0x7fffu + ((u>>16)&1u)) >> 16);
}
__device__ __forceinline__ float b2f(u16 u){
  return __uint_as_float(((unsigned)u)<<16);
}

// ---- swizzled bf16 LDS tile: [128][128] bf16 (32KB), byte = row*256+e*2,
// XOR ((row&7)<<4)  (G4 bank-conflict fix) ----
__device__ __forceinline__ bf16x8 ldfrag(const u16* base, int row, int e){
  int byte = (row*256 + e*2) ^ ((row&7)<<4);
  return *(const bf16x8*)((const char*)base + byte);
}
// stage bf16 row-major [128 x 128] (row stride srs elems) -> swizzled tile
__device__ __forceinline__ void stage_lin_bf(u16* dst, const u16* src, int srs, int t){
  #pragma unroll
  for(int it=0; it<8; ++it){
    int idx = t + it*256; int r = idx>>4, c8 = idx&15;
    int byte = (r*256 + c8*16) ^ ((r&7)<<4);
    *(uint4*)((char*)dst + byte) = *(const uint4*)(src + r*srs + c8*8);
  }
}
// stage bf16 row-major with per-element scale+offset: val*sc + off
__device__ __forceinline__ void stage_lin_bf_s(u16* dst, const u16* src, int srs,
    int t, float sc, float off){
  #pragma unroll
  for(int it=0; it<8; ++it){
    int idx = t + it*256; int r = idx>>4, c8 = idx&15;
    u16 tmp[8]; *(uint4*)tmp = *(const uint4*)(src + r*srs + c8*8);
    #pragma unroll
    for(int u=0;u<8;u++) tmp[u] = f2bu(fmaf(b2f(tmp[u]), sc, off));
    int byte = (r*256 + c8*16) ^ ((r&7)<<4);
    *(uint4*)((char*)dst + byte) = *(uint4*)tmp;
  }
}
// stage fp32 row-major [128 x 128] -> bf16 swizzled tile
__device__ __forceinline__ void stage_lin_f32(u16* dst, const float* src, int srs, int t){
  #pragma unroll
  for(int it=0; it<8; ++it){
    int idx = t + it*256; int r = idx>>4, c8 = idx&15;
    F4 v0, v1;
    v0.v = *(const float4*)(src + r*srs + c8*8);
    v1.v = *(const float4*)(src + r*srs + c8*8 + 4);
    u16 tmp[8];
    #pragma unroll
    for(int u=0;u<4;u++){ tmp[u] = f2bu(v0.f[u]); tmp[4+u] = f2bu(v1.f[u]); }
    int byte = (r*256 + c8*16) ^ ((r&7)<<4);
    *(uint4*)((char*)dst + byte) = *(uint4*)tmp;
  }
}
// stage TRANSPOSED from bf16 source: dst[d][j] = src[j][d]
__device__ __forceinline__ void stage_tr_bf(u16* dst, const u16* src, int srs, int t){
  int j0 = (t & 63)*2; int wv = t>>6;
  #pragma unroll
  for(int it=0; it<2; ++it){
    int d0 = wv*16 + it*64;
    u16 a0[16], a1[16];
    *(uint4*)&a0[0] = *(const uint4*)(src + j0*srs + d0);
    *(uint4*)&a0[8] = *(const uint4*)(src + j0*srs + d0 + 8);
    *(uint4*)&a1[0] = *(const uint4*)(src + (j0+1)*srs + d0);
    *(uint4*)&a1[8] = *(const uint4*)(src + (j0+1)*srs + d0 + 8);
    #pragma unroll
    for(int dc=0; dc<16; ++dc){
      int d = d0 + dc;
      unsigned pk = (unsigned)a0[dc] | ((unsigned)a1[dc]<<16);
      int byte = (d*256 + j0*2) ^ ((d&7)<<4);
      *(unsigned*)((char*)dst + byte) = pk;
    }
  }
}
// stage TRANSPOSED from bf16 source with per-element scale+offset
__device__ __forceinline__ void stage_tr_bf_s(u16* dst, const u16* src, int srs,
    int t, float sc, float off){
  int j0 = (t & 63)*2; int wv = t>>6;
  #pragma unroll
  for(int it=0; it<2; ++it){
    int d0 = wv*16 + it*64;
    u16 a0[16], a1[16];
    *(uint4*)&a0[0] = *(const uint4*)(src + j0*srs + d0);
    *(uint4*)&a0[8] = *(const uint4*)(src + j0*srs + d0 + 8);
    *(uint4*)&a1[0] = *(const uint4*)(src + (j0+1)*srs + d0);
    *(uint4*)&a1[8] = *(const uint4*)(src + (j0+1)*srs + d0 + 8);
    #pragma unroll
    for(int dc=0; dc<16; ++dc){
      int d = d0 + dc;
      unsigned pk = (unsigned)f2bu(fmaf(b2f(a0[dc]), sc, off)) |
                    ((unsigned)f2bu(fmaf(b2f(a1[dc]), sc, off))<<16);
      int byte = (d*256 + j0*2) ^ ((d&7)<<4);
      *(unsigned*)((char*)dst + byte) = pk;
    }
  }
}

// bijective XCD-aware tile swizzle: returns (tile_n, tile_m)
__device__ __forceinline__ int2 swz_tile(){
  int nx = gridDim.x;
  int nwg = gridDim.x*gridDim.y;
  int lin = blockIdx.y*nx + blockIdx.x;
  int q = nwg>>3, r = nwg&7;
  int xcd = lin&7, idx = lin>>3;
  int nl = (xcd<r) ? (xcd*(q+1)+idx) : (r*(q+1)+(xcd-r)*q+idx);
  return make_int2(nl % nx, nl / nx);
}

// ------- embedding + layer-0 LN1 fused (+ kstab init in block 0) ---------
__global__ __launch_bounds__(256) void k_embed_ln(const float* __restrict__ x,
    const float* __restrict__ lw, const float* __restrict__ lb,
    const float* __restrict__ pe, const float* __restrict__ g,
    const float* __restrict__ bta, float* __restrict__ h,
    u16* __restrict__ y, unsigned* __restrict__ kstab){
  if(blockIdx.x==0 && threadIdx.x<64) kstab[threadIdx.x] = 0u;
  int wave = threadIdx.x >> 6; int lane = threadIdx.x & 63;
  int row = blockIdx.x*4 + wave;
  int s = row & (Ss-1);
  float xv = x[row];
  float x1 = xv*lw[lane]    + lb[lane]    + pe[s*DIMc + lane];
  float x2 = xv*lw[lane+64] + lb[lane+64] + pe[s*DIMc + lane+64];
  h[row*DIMc+lane]    = x1;
  h[row*DIMc+lane+64] = x2;
  float sm = x1+x2, sq = x1*x1 + x2*x2;
  #pragma unroll
  for(int m=1;m<64;m<<=1){ sm += __shfl_xor(sm,m,64); sq += __shfl_xor(sq,m,64); }
  float mu = sm * (1.0f/128.0f);
  float var = sq*(1.0f/128.0f) - mu*mu;
  float rs = rsqrtf(var + 1e-5f);
  y[row*DIMc+lane]    = f2bu((x1-mu)*rs*g[lane]+bta[lane]);
  y[row*DIMc+lane+64] = f2bu((x2-mu)*rs*g[lane+64]+bta[lane+64]);
}

// ---------------- layernorm: fp32 in -> bf16 out ----------------
__global__ __launch_bounds__(256) void k_ln(const float* __restrict__ in,
    const float* __restrict__ g, const float* __restrict__ bta,
    u16* __restrict__ out){
  int wave = threadIdx.x >> 6; int lane = threadIdx.x & 63;
  int row = blockIdx.x*4 + wave;
  const float* r = in + row*DIMc;
  float x1 = r[lane], x2 = r[lane+64];
  float s = x1+x2, sq = x1*x1 + x2*x2;
  #pragma unroll
  for(int m=1;m<64;m<<=1){ s += __shfl_xor(s,m,64); sq += __shfl_xor(sq,m,64); }
  float mu = s * (1.0f/128.0f);
  float var = sq*(1.0f/128.0f) - mu*mu;
  float rs = rsqrtf(var + 1e-5f);
  out[row*DIMc+lane]    = f2bu((x1-mu)*rs*g[lane]+bta[lane]);
  out[row*DIMc+lane+64] = f2bu((x2-mu)*rs*g[lane+64]+bta[lane+64]);
}

// --------- prep: transpose+convert ALL weights to bf16 [N][K] ------------
// Per block: one 128(k) x 128(n) tile via LDS transpose, coalesced both ways.
// blocks 0..47: qkv (l, m, nt) -> qkvT[(l*3+m)*1024 + n][128]
// blocks 48..63: wo (l, kt)    -> woT[l][n][1024]
// blocks 64..71: ff1 (l, nt)   -> ff1T[l*512 + n][128]
// blocks 72..79: ff2 (l, kt)   -> ff2T[l][n][512]
__global__ __launch_bounds__(256) void k_prep(const float* __restrict__ wq,
    const float* __restrict__ wk, const float* __restrict__ wv,
    const float* __restrict__ ff1, const float* __restrict__ wo,
    const float* __restrict__ ff2, u16* __restrict__ qkvT,
    u16* __restrict__ ff1T, u16* __restrict__ woT, u16* __restrict__ ff2T){
  __shared__ u16 tile[128][136];   // 16B-aligned rows
  int blk = blockIdx.x, t = threadIdx.x;
  const float* src; u16* dst; int srcN, dstK, k0, n0;
  if(blk < 48){
    int l = blk/24, m = (blk%24)>>3, nt = blk&7;
    const float* W = (m==0) ? wq : ((m==1) ? wk : wv);
    src = W + l*131072; srcN = 1024; k0 = 0; n0 = nt*128;
    dst = qkvT + ((size_t)(l*3+m)*1024 + n0)*128; dstK = 128;
  } else if(blk < 64){
    int i = blk-48; int l = i>>3, kt = i&7;
    src = wo + l*131072; srcN = 128; k0 = kt*128; n0 = 0;
    dst = woT + (size_t)l*131072; dstK = 1024;
  } else if(blk < 72){
    int i = blk-64; int l = i>>2, nt = i&3;
    src = ff1 + l*65536; srcN = 512; k0 = 0; n0 = nt*128;
    dst = ff1T + ((size_t)l*512 + n0)*128; dstK = 128;
  } else {
    int i = blk-72; int l = i>>2, kt = i&3;
    src = ff2 + l*65536; srcN = 128; k0 = kt*128; n0 = 0;
    dst = ff2T + (size_t)l*65536; dstK = 512;
  }
  #pragma unroll
  for(int it=0; it<16; ++it){
    int idx = t + it*256; int kk = idx>>5, n4 = idx&31;
    F4 v; v.v = *(const float4*)(src + (size_t)(k0+kk)*srcN + n0 + n4*4);
    #pragma unroll
    for(int j=0;j<4;j++) tile[n4*4+j][kk] = f2bu(v.f[j]);
  }
  __syncthreads();
  #pragma unroll
  for(int it=0; it<8; ++it){
    int idx = t + it*256; int n = idx>>4, kq = idx&15;
    *(uint4*)(dst + (size_t)n*dstK + k0 + kq*8) = *(uint4*)&tile[n][kq*8];
  }
}

// ------------ 128x128 K-resident MFMA GEMM (K=128), bf16 A + bf16 BT -----
// BT: pre-transposed weights [N][128]. QKV3: BT = layer base covering 3 mats.
template<bool QKV3, bool BIAS, bool GELU>
__global__ __launch_bounds__(256) void k_gemm128(const u16* __restrict__ A,
    const u16* __restrict__ BT, const float* __restrict__ bias,
    u16* __restrict__ C0, u16* __restrict__ C1, u16* __restrict__ C2,
    int N){
  __shared__ __align__(16) u16 As[16384];
  __shared__ __align__(16) u16 Bs[16384];
  int2 tt = swz_tile();
  int tn = tt.x, m0 = tt.y*128;
  const u16* Bbase; u16* C; int n0;
  if(QKV3){
    int widx = tn>>3; n0 = (tn&7)*128;
    Bbase = BT + (size_t)widx*131072 + (size_t)n0*128;
    C = (widx==0) ? C0 : ((widx==1) ? C1 : C2);
  } else { n0 = tn*128; Bbase = BT + (size_t)n0*128; C = C0; }
  int t = threadIdx.x; int lane = t&63, w = t>>6;
  int fr = lane&15, kc = lane>>4;
  stage_lin_bf(As, A + (size_t)m0*128, 128, t);
  stage_lin_bf(Bs, Bbase, 128, t);
  __syncthreads();
  f32x4 acc[2][8] = {};
  #pragma unroll
  for(int ks=0; ks<4; ++ks){
    bf16x8 a[2];
    #pragma unroll
    for(int i=0;i<2;i++) a[i] = ldfrag(As, w*32+i*16+fr, ks*32+kc*8);
    bf16x8 bm[8];
    #pragma unroll
    for(int cb=0;cb<8;cb++) bm[cb] = ldfrag(Bs, cb*16+fr, ks*32+kc*8);
    #pragma unroll
    for(int i=0;i<2;i++)
      #pragma unroll
      for(int cb=0;cb<8;cb++)
        acc[i][cb] = __builtin_amdgcn_mfma_f32_16x16x32_bf16(a[i], bm[cb], acc[i][cb], 0,0,0);
  }
  #pragma unroll
  for(int i=0;i<2;i++){
    #pragma unroll
    for(int r=0;r<4;r++){
      int row = m0 + w*32 + i*16 + kc*4 + r;
      #pragma unroll
      for(int cb=0;cb<8;cb++){
        int col = n0 + cb*16 + fr;
        float val = acc[i][cb][r];
        if(BIAS) val += bias[col];
        if(GELU) val = gelu_f(val);
        C[(size_t)row*N + col] = f2bu(val);
      }
    }
  }
}

// ------------ direct-fragment GEMM (no LDS, no barriers) -----------------
// A bf16 [M][K] row-major, BT bf16 [N][K] row-major (pre-transposed weights).
// C fp32 [M][N]: C = C + A@B + bias  (residual in place). Grid (N/64, M/64).
__global__ __launch_bounds__(256) void k_gemm_direct(const u16* __restrict__ A,
    const u16* __restrict__ BT, const float* __restrict__ bias,
    float* __restrict__ C, int N, int K){
  int2 tt = swz_tile();
  int n0 = tt.x*64, m0 = tt.y*64;
  int t = threadIdx.x; int wid = t>>6, lane = t&63;
  int wr = wid>>1, wc = wid&1;
  int fr = lane&15, kc = lane>>4;
  const u16* a0p = A  + (size_t)(m0+wr*32+fr)*K    + kc*8;
  const u16* a1p = A  + (size_t)(m0+wr*32+16+fr)*K + kc*8;
  const u16* b0p = BT + (size_t)(n0+wc*32+fr)*K    + kc*8;
  const u16* b1p = BT + (size_t)(n0+wc*32+16+fr)*K + kc*8;
  f32x4 acc[2][2] = {};
  #pragma unroll 4
  for(int k0=0; k0<K; k0+=32){
    bf16x8 af0 = *(const bf16x8*)(a0p + k0);
    bf16x8 af1 = *(const bf16x8*)(a1p + k0);
    bf16x8 bf0 = *(const bf16x8*)(b0p + k0);
    bf16x8 bf1 = *(const bf16x8*)(b1p + k0);
    acc[0][0] = __builtin_amdgcn_mfma_f32_16x16x32_bf16(af0, bf0, acc[0][0], 0,0,0);
    acc[0][1] = __builtin_amdgcn_mfma_f32_16x16x32_bf16(af0, bf1, acc[0][1], 0,0,0);
    acc[1][0] = __builtin_amdgcn_mfma_f32_16x16x32_bf16(af1, bf0, acc[1][0], 0,0,0);
    acc[1][1] = __builtin_amdgcn_mfma_f32_16x16x32_bf16(af1, bf1, acc[1][1], 0,0,0);
  }
  #pragma unroll
  for(int i=0;i<2;i++){
    #pragma unroll
    for(int r=0;r<4;r++){
      int row = m0 + wr*32 + i*16 + kc*4 + r;
      #pragma unroll
      for(int j=0;j<2;j++){
        int col = n0 + wc*32 + j*16 + fr;
        float val = acc[i][j][r] + bias[col];
        C[(size_t)row*N+col] += val;
      }
    }
  }
}

// ------------- FAVOR+ features via MFMA, q+k in ONE dispatch -------------
__global__ __launch_bounds__(256) void k_featboth(
    u16* __restrict__ qbuf, u16* __restrict__ kbuf,
    const float* __restrict__ proj, unsigned* __restrict__ kstab){
  __shared__ __align__(16) u16 xs[16384];
  __shared__ __align__(16) u16 ps[16384];
  __shared__ float diag_s[128];
  __shared__ unsigned hmax[8];
  int blk = blockIdx.x;
  bool isq = blk < 512;
  int r0 = (blk & 511)*128;
  u16* xin = isq ? qbuf : kbuf;
  int t = threadIdx.x; int lane = t&63, w = t>>6;
  int fr = lane&15, kc = lane>>4;
  const float norm  = 0.29730177875068026f;   // 128^-0.25
  const float ratio = 0.08838834764831845f;   // 128^-0.5
  if(!isq && t<8) hmax[t] = 0u;
  stage_lin_bf(xs, xin + (size_t)r0*128, 128, t);
  stage_lin_f32(ps, proj, 128, t);
  { // diag: 2 threads per row, 64 elems each
    int r = t>>1, half = t&1;
    const u16* rp = xin + (size_t)(r0+r)*128 + half*64;
    float ss = 0.f;
    #pragma unroll
    for(int u4=0; u4<8; ++u4){
      u16 tmp[8]; *(uint4*)tmp = *(const uint4*)(rp + u4*8);
      #pragma unroll
      for(int u=0;u<8;u++){ float f = b2f(tmp[u]); ss += f*f; }
    }
    ss += __shfl_xor(ss, 1, 64);
    if(half==0) diag_s[r] = 0.5f*norm*norm*ss;
  }
  __syncthreads();
  f32x4 acc[2][8] = {};
  #pragma unroll
  for(int ks=0; ks<4; ++ks){
    bf16x8 a[2];
    #pragma unroll
    for(int i=0;i<2;i++) a[i] = ldfrag(xs, w*32+i*16+fr, ks*32+kc*8);
    bf16x8 bm[8];
    #pragma unroll
    for(int cb=0;cb<8;cb++) bm[cb] = ldfrag(ps, cb*16+fr, ks*32+kc*8);
    #pragma unroll
    for(int i=0;i<2;i++)
      #pragma unroll
      for(int cb=0;cb<8;cb++)
        acc[i][cb] = __builtin_amdgcn_mfma_f32_16x16x32_bf16(a[i], bm[cb], acc[i][cb], 0,0,0);
  }
  __syncthreads();   // all xs/ps reads complete before reuse
  #pragma unroll
  for(int i=0;i<2;i++){
    #pragma unroll
    for(int r=0;r<4;r++){
      int row = w*32 + i*16 + kc*4 + r;
      float dg = diag_s[row];
      float rmax = acc[i][0][r];
      #pragma unroll
      for(int cb=1;cb<8;cb++) rmax = fmaxf(rmax, acc[i][cb][r]);
      #pragma unroll
      for(int msk=1;msk<16;msk<<=1) rmax = fmaxf(rmax, __shfl_xor(rmax, msk, 64));
      if(isq){
        float base = -dg - norm*rmax;
        #pragma unroll
        for(int cb=0;cb<8;cb++){
          float val = ratio*(expf(fmaf(norm, acc[i][cb][r], base)) + 1e-4f);
          int byte = (row*256 + (cb*16+fr)*2) ^ ((row&7)<<4);
          *(u16*)((char*)xs + byte) = f2bu(val);
        }
      } else {
        if(fr==0) atomicMax(&hmax[row&7], fkey(norm*rmax));
        #pragma unroll
        for(int cb=0;cb<8;cb++){
          float val = expf(fmaf(norm, acc[i][cb][r], -dg));
          int byte = (row*256 + (cb*16+fr)*2) ^ ((row&7)<<4);
          *(u16*)((char*)xs + byte) = f2bu(val);
        }
      }
    }
  }
  __syncthreads();
  // coalesced copy out of the restaged tile
  #pragma unroll
  for(int it=0; it<8; ++it){
    int idx = t + it*256; int r = idx>>4, c8 = idx&15;
    int byte = (r*256 + c8*16) ^ ((r&7)<<4);
    *(uint4*)(xin + (size_t)(r0+r)*128 + c8*8) = *(uint4*)((char*)xs + byte);
  }
  if(!isq){
    int b = r0 >> 14;
    if(t<8) atomicMax(&kstab[b*8 + t], hmax[t]);
  }
}

// ------------- attention phase 1 (MFMA): kv = kp^T v, ksum = sum kp ------
__global__ __launch_bounds__(256) void k_attn1m(const u16* __restrict__ kp,
    const u16* __restrict__ v, u16* __restrict__ kvc, float* __restrict__ ksc,
    const unsigned* __restrict__ kstab){
  __shared__ __align__(16) u16 kt[16384];
  __shared__ __align__(16) u16 vt[16384];
  int bc = blockIdx.x; int c = bc&15, bh = bc>>4, b = bh>>3, hh = bh&7;
  int t = threadIdx.x; int lane = t&63, w = t>>6;
  int fr = lane&15, kc = lane>>4;
  int s0 = c*128;
  const float ratio = 0.08838834764831845f;
  float stab = funkey(kstab[bh]);
  float csc = ratio * expf(-stab);
  float reps = ratio * 1e-4f;
  const u16* kb = kp + (size_t)((b*Ss+s0)*Hh + hh)*128;
  const u16* vb = v  + (size_t)((b*Ss+s0)*Hh + hh)*128;
  stage_tr_bf_s(kt, kb, 1024, t, csc, reps);
  stage_tr_bf(vt, vb, 1024, t);
  __syncthreads();
  f32x4 acc[2][8] = {};
  f32x4 ks[2] = {};
  bf16x8 bones;
  #pragma unroll
  for(int e=0;e<8;e++) bones[e] = (fr==0) ? (__bf16)1.0f : (__bf16)0.0f;
  #pragma unroll
  for(int js=0;js<4;js++){
    bf16x8 am[2];
    #pragma unroll
    for(int i=0;i<2;i++) am[i] = ldfrag(kt, w*32+i*16+fr, js*32+kc*8);
    bf16x8 bv[8];
    #pragma unroll
    for(int cb=0;cb<8;cb++) bv[cb] = ldfrag(vt, cb*16+fr, js*32+kc*8);
    #pragma unroll
    for(int i=0;i<2;i++){
      ks[i] = __builtin_amdgcn_mfma_f32_16x16x32_bf16(am[i], bones, ks[i], 0,0,0);
      #pragma unroll
      for(int cb=0;cb<8;cb++)
        acc[i][cb] = __builtin_amdgcn_mfma_f32_16x16x32_bf16(am[i], bv[cb], acc[i][cb], 0,0,0);
    }
  }
  u16* kvb = kvc + (size_t)bc*16384;
  #pragma unroll
  for(int i=0;i<2;i++){
    #pragma unroll
    for(int r=0;r<4;r++){
      int m = w*32 + i*16 + kc*4 + r;
      #pragma unroll
      for(int cb=0;cb<8;cb++) kvb[m*128 + cb*16 + fr] = f2bu(acc[i][cb][r]);
      if(fr==0) ksc[bc*128 + m] = ks[i][r];
    }
  }
}

// --- phase 1.5 fused: blocks 0..1023 scan kvc (bf16 pairs), 1024..1039 ksc
__global__ __launch_bounds__(256) void k_prefix2(unsigned* __restrict__ kvc,
    float* __restrict__ ksc){
  int blk = blockIdx.x;
  if(blk < 1024){
    int bh = blk >> 5; int pos = (blk & 31)*256 + threadIdx.x; // uint idx
    int base = bh*16*8192 + pos;
    float a0 = 0.f, a1 = 0.f;
    #pragma unroll
    for(int c=0;c<16;c++){
      unsigned pk = kvc[base + c*8192];
      float x0 = b2f((u16)pk), x1 = b2f((u16)(pk>>16));
      kvc[base + c*8192] = (unsigned)f2bu(a0) | ((unsigned)f2bu(a1)<<16);
      a0 += x0; a1 += x1;
    }
  } else {
    int e = (blk-1024)*256 + threadIdx.x;
    int bh = e>>7, m = e&127;
    float a = 0.f;
    #pragma unroll
    for(int c=0;c<16;c++){
      int idx = (bh*16+c)*128 + m;
      float xv = ksc[idx]; ksc[idx] = a; a += xv;
    }
  }
}

// ------------- attention phase 2 (MFMA): per-chunk output ----------------
__global__ __launch_bounds__(256) void k_attn2m(const u16* __restrict__ qp,
    const u16* __restrict__ kp, const u16* __restrict__ v,
    const u16* __restrict__ kvc, const float* __restrict__ ksc,
    u16* __restrict__ o, const unsigned* __restrict__ kstab){
  __shared__ __align__(16) u16 qs[16384];  // qp -> P
  __shared__ __align__(16) u16 bs[16384];  // kp -> v^T -> kv^T
  __shared__ float ksum_s[128];
  int bc = blockIdx.x; int c = bc&15, bh = bc>>4, b = bh>>3, hh = bh&7;
  int t = threadIdx.x; int lane = t&63, w = t>>6;
  int fr = lane&15, kc = lane>>4;
  int s0 = c*128;
  const float ratio = 0.08838834764831845f;
  float stab = funkey(kstab[bh]);
  float csc = ratio * expf(-stab);
  float reps = ratio * 1e-4f;
  const u16* qb = qp + (size_t)((b*Ss+s0)*Hh + hh)*128;
  const u16* kb = kp + (size_t)((b*Ss+s0)*Hh + hh)*128;
  const u16* vb = v  + (size_t)((b*Ss+s0)*Hh + hh)*128;
  const u16* kvb = kvc + (size_t)bc*16384;
  stage_lin_bf(qs, qb, 1024, t);
  stage_lin_bf_s(bs, kb, 1024, t, csc, reps);
  if(t<128) ksum_s[t] = ksc[bc*128 + t];
  __syncthreads();
  bf16x8 aq[2][4];
  #pragma unroll
  for(int i=0;i<2;i++)
    #pragma unroll
    for(int ks=0;ks<4;ks++)
      aq[i][ks] = ldfrag(qs, w*32+i*16+fr, ks*32+kc*8);
  // S = qp @ kp^T
  f32x4 sacc[2][8] = {};
  #pragma unroll
  for(int ks=0;ks<4;ks++){
    bf16x8 bk[8];
    #pragma unroll
    for(int cb=0;cb<8;cb++) bk[cb] = ldfrag(bs, cb*16+fr, ks*32+kc*8);
    #pragma unroll
    for(int i=0;i<2;i++)
      #pragma unroll
      for(int cb=0;cb<8;cb++)
        sacc[i][cb] = __builtin_amdgcn_mfma_f32_16x16x32_bf16(aq[i][ks], bk[cb], sacc[i][cb], 0,0,0);
  }
  __syncthreads();
  // masked P -> qs (bf16); stage v^T -> bs
  #pragma unroll
  for(int i=0;i<2;i++){
    #pragma unroll
    for(int cb=0;cb<8;cb++){
      #pragma unroll
      for(int r=0;r<4;r++){
        int prow = w*32 + i*16 + kc*4 + r;
        int pcol = cb*16 + fr;
        float pv = (pcol > prow) ? 0.f : sacc[i][cb][r];
        int byte = (prow*256 + pcol*2) ^ ((prow&7)<<4);
        *(u16*)((char*)qs + byte) = f2bu(pv);
      }
    }
  }
  stage_tr_bf(bs, vb, 1024, t);
  __syncthreads();
  // num = P @ v ; den = P @ ones
  f32x4 nacc[2][8] = {};
  f32x4 dacc[2] = {};
  bf16x8 bones;
  #pragma unroll
  for(int e=0;e<8;e++) bones[e] = (fr==0) ? (__bf16)1.0f : (__bf16)0.0f;
  #pragma unroll
  for(int js=0;js<4;js++){
    bf16x8 ap[2];
    #pragma unroll
    for(int i=0;i<2;i++) ap[i] = ldfrag(qs, w*32+i*16+fr, js*32+kc*8);
    bf16x8 bv[8];
    #pragma unroll
    for(int cb=0;cb<8;cb++) bv[cb] = ldfrag(bs, cb*16+fr, js*32+kc*8);
    #pragma unroll
    for(int i=0;i<2;i++){
      dacc[i] = __builtin_amdgcn_mfma_f32_16x16x32_bf16(ap[i], bones, dacc[i], 0,0,0);
      #pragma unroll
      for(int cb=0;cb<8;cb++)
        nacc[i][cb] = __builtin_amdgcn_mfma_f32_16x16x32_bf16(ap[i], bv[cb], nacc[i][cb], 0,0,0);
    }
  }
  __syncthreads();
  stage_tr_bf(bs, kvb, 128, t);
  __syncthreads();
  // num += qp @ kv_excl ; den += qp @ ksum_excl
  #pragma unroll
  for(int ms=0;ms<4;ms++){
    bf16x8 bkv[8];
    #pragma unroll
    for(int cb=0;cb<8;cb++) bkv[cb] = ldfrag(bs, cb*16+fr, ms*32+kc*8);
    bf16x8 bks;
    #pragma unroll
    for(int e=0;e<8;e++) bks[e] = (fr==0) ? (__bf16)ksum_s[ms*32+kc*8+e] : (__bf16)0.0f;
    #pragma unroll
    for(int i=0;i<2;i++){
      dacc[i] = __builtin_amdgcn_mfma_f32_16x16x32_bf16(aq[i][ms], bks, dacc[i], 0,0,0);
      #pragma unroll
      for(int cb=0;cb<8;cb++)
        nacc[i][cb] = __builtin_amdgcn_mfma_f32_16x16x32_bf16(aq[i][ms], bkv[cb], nacc[i][cb], 0,0,0);
    }
  }
  #pragma unroll
  for(int i=0;i<2;i++){
    #pragma unroll
    for(int r=0;r<4;r++){
      float den = __shfl(dacc[i][r], lane & 48, 64);
      float inv = 1.0f/(den + 1e-6f);
      int row = w*32 + i*16 + kc*4 + r;
      u16* ob = o + (size_t)((b*Ss+s0+row)*Hh + hh)*128;
      #pragma unroll
      for(int cb=0;cb<8;cb++)
        ob[cb*16 + fr] = f2bu(nacc[i][cb][r] * inv);
    }
  }
}

// ------------- pooling + classifier --------------------------------------
__global__ __launch_bounds__(256) void k_pool(const float* __restrict__ h,
    float* __restrict__ pw){
  __shared__ float part[256];
  int blk = blockIdx.x; int b = blk>>4, c = blk&15;
  int t = threadIdx.x; int half = t>>7;
  float s = 0.f;
  int s0 = c*128 + half*64;
  for(int si=s0; si<s0+64; ++si) s += h[(b*Ss+si)*128 + (t&127)];
  part[t] = s;
  __syncthreads();
  if(t<128) pw[blk*128 + t] = part[t] + part[t+128];
}
__global__ __launch_bounds__(128) void k_cls(const float* __restrict__ pw,
    const float* __restrict__ fw, const float* __restrict__ fb,
    float* __restrict__ out){
  __shared__ float pool_s[128];
  int b = blockIdx.x; int t = threadIdx.x;
  float s = 0.f;
  for(int c=0;c<16;c++) s += pw[(b*16+c)*128 + t];
  pool_s[t] = s * (1.0f/2048.0f);
  __syncthreads();
  if(t<10){
    float a = fb[t];
    for(int d=0; d<128; ++d) a += pool_s[d]*fw[d*10+t];
    out[b*10+t] = a;
  }
}

extern "C" void kernel_launch(void* const* d_in, const int* in_sizes, int n_in,
                              void* d_out, int out_size, void* d_ws, size_t ws_size,
                              hipStream_t stream){
  (void)in_sizes; (void)n_in; (void)out_size; (void)ws_size;
  const float* x     = (const float*)d_in[0];
  const float* lin_w = (const float*)d_in[1];
  const float* lin_b = (const float*)d_in[2];
  const float* pe    = (const float*)d_in[3];
  const float* proj  = (const float*)d_in[4];
  const float* ln1_g = (const float*)d_in[5];
  const float* ln1_b = (const float*)d_in[6];
  const float* wq    = (const float*)d_in[7];
  const float* wk    = (const float*)d_in[8];
  const float* wv    = (const float*)d_in[9];
  const float* wo    = (const float*)d_in[10];
  const float* wo_b  = (const float*)d_in[11];
  const float* ln2_g = (const float*)d_in[12];
  const float* ln2_b = (const float*)d_in[13];
  const float* ff1w  = (const float*)d_in[14];
  const float* ff1b  = (const float*)d_in[15];
  const float* ff2w  = (const float*)d_in[16];
  const float* ff2b  = (const float*)d_in[17];
  const float* finw  = (const float*)d_in[18];
  const float* finb  = (const float*)d_in[19];
  float* out = (float*)d_out;

  // workspace layout (in floats; bf16 buffers use half-float slots)
  float* ws  = (float*)d_ws;
  float* h    = ws;               // fp32 [8192][128]
  u16*  y    = (u16*)(h + 1048576);               // bf16 [8192][128]
  u16*  q    = (u16*)(h + 1048576 + 524288);      // bf16 [8192][1024]
  u16*  k    = q + 8388608;       // bf16 [8192][1024]
  u16*  v    = k + 8388608;       // bf16
  u16*  o    = v + 8388608;       // bf16
  u16*  kvc  = o + 8388608;       // bf16 [32][16][128][128]
  float* ksc  = (float*)(kvc + 8388608);  // fp32 [32][16][128]
  float* pw   = ksc + 65536;
  unsigned* kstab = (unsigned*)(pw + 8192);   // [2][32]
  u16*  woT  = (u16*)(kstab + 64);            // bf16 [2][128][1024]
  u16*  ff2T = woT + 262144;                  // bf16 [2][128][512]
  u16*  qkvT = ff2T + 131072;                 // bf16 [2][3][1024][128]
  u16*  ff1T = qkvT + 786432;                 // bf16 [2][512][128]

  k_embed_ln<<<2048,256,0,stream>>>(x, lin_w, lin_b, pe, ln1_g, ln1_b, h, y, kstab);
  k_prep<<<80,256,0,stream>>>(wq, wk, wv, ff1w, wo, ff2w, qkvT, ff1T, woT, ff2T);
  for(int l=0;l<2;l++){
    const float* projl = proj + l*Mf*DHc;
    if(l) k_ln<<<2048,256,0,stream>>>(h, ln1_g + l*DIMc, ln1_b + l*DIMc, y);
    k_gemm128<true,false,false><<<dim3(24,64),256,0,stream>>>(
        y, qkvT + (size_t)l*393216, nullptr, q, k, v, INNERc);
    k_featboth<<<1024,256,0,stream>>>(q, k, projl, kstab + l*32);
    k_attn1m<<<512,256,0,stream>>>(k, v, kvc, ksc, kstab + l*32);
    k_prefix2<<<1040,256,0,stream>>>((unsigned*)kvc, ksc);
    k_attn2m<<<512,256,0,stream>>>(q, k, v, kvc, ksc, o, kstab + l*32);
    k_gemm_direct<<<dim3(2,128),256,0,stream>>>(o, woT + l*131072, wo_b + l*DIMc, h, DIMc, INNERc);
    k_ln<<<2048,256,0,stream>>>(h, ln2_g + l*DIMc, ln2_b + l*DIMc, y);
    k_gemm128<false,true,true><<<dim3(4,64),256,0,stream>>>(
        y, ff1T + (size_t)l*65536, ff1b + l*FFc, q, nullptr, nullptr, FFc);
    k_gemm_direct<<<dim3(2,128),256,0,stream>>>(q, ff2T + l*65536, ff2b + l*DIMc, h, DIMc, FFc);
  }
  k_pool<<<64,256,0,stream>>>(h, pw);
  k_cls<<<4,128,0,stream>>>(pw, finw, finb, out);
}